// Round 3
// baseline (231.586 us; speedup 1.0000x reference)
//
#include <hip/hip_runtime.h>

// cumprod along dim 1 of (ROWS, N) fp32, row-major.
// Register-resident scan: no LDS tile, one tiny barrier per row.
//
// Decomposition: one 512-thread block per row; wave w owns elements
// [w*1024, (w+1)*1024). Lane l holds quads at (v*64+l)*4 for v=0..3,
// so BOTH the float4 loads and stores are natively coalesced.
// Scan = in-quad serial (3 muls) + per-v wave shuffle-scan of quad
// totals with a running carry, then one 32 B LDS exchange of the 8
// wave totals. Output stores are nontemporal so the streaming output
// doesn't evict the L3-resident input.

#define N      8192
#define T      512
#define NW     (T / 64)          // 8 waves per block
#define QV     (N / (T * 4))     // 4 quad-iterations per thread

// clang builtin vector (HIP's float4 is a struct; nontemporal builtin rejects it)
typedef float f32x4 __attribute__((ext_vector_type(4)));

__global__ __launch_bounds__(T) void cumprod_rows_kernel(
    const float* __restrict__ x, float* __restrict__ out, int n_rows)
{
    __shared__ float wsum[NW];

    const int row = blockIdx.x;
    if (row >= n_rows) return;
    const int tid  = threadIdx.x;
    const int lane = tid & 63;
    const int wid  = tid >> 6;

    const float* __restrict__ xr   = x   + (size_t)row * N + (size_t)wid * (N / NW);
    float*       __restrict__ outr = out + (size_t)row * N + (size_t)wid * (N / NW);

    // ---- coalesced loads: quad (v, lane) at element (v*64+lane)*4 ----
    f32x4 d[QV];
#pragma unroll
    for (int v = 0; v < QV; ++v)
        d[v] = *reinterpret_cast<const f32x4*>(xr + (v * 64 + lane) * 4);

    // ---- scan ----
    float carry = 1.0f;          // product of all quads in this wave before v
    float coef[QV];              // exclusive prefix (within wave) for quad v
#pragma unroll
    for (int v = 0; v < QV; ++v) {
        // in-quad inclusive scan, kept in d
        d[v].y *= d[v].x;
        d[v].z *= d[v].y;
        d[v].w *= d[v].z;
        // wave-level inclusive shuffle-scan of quad totals
        float inc = d[v].w;
#pragma unroll
        for (int off = 1; off < 64; off <<= 1) {
            const float o = __shfl_up(inc, off, 64);
            if (lane >= off) inc *= o;
        }
        float ex = __shfl_up(inc, 1, 64);
        if (lane == 0) ex = 1.0f;
        coef[v] = carry * ex;
        carry  *= __shfl(inc, 63, 64);   // wave total over quads of this v
    }

    // ---- one tiny barrier: exchange wave totals ----
    if (lane == 63) wsum[wid] = carry;   // carry == product of wave's 1024 elems
    __syncthreads();

    float wpre = 1.0f;
#pragma unroll
    for (int w = 0; w < NW - 1; ++w)
        if (w < wid) wpre *= wsum[w];

    // ---- coalesced nontemporal stores ----
#pragma unroll
    for (int v = 0; v < QV; ++v) {
        const float f = wpre * coef[v];
        f32x4 o = d[v];
        o.x *= f; o.y *= f; o.z *= f; o.w *= f;
        __builtin_nontemporal_store(o, reinterpret_cast<f32x4*>(outr + (v * 64 + lane) * 4));
    }
}

extern "C" void kernel_launch(void* const* d_in, const int* in_sizes, int n_in,
                              void* d_out, int out_size, void* d_ws, size_t ws_size,
                              hipStream_t stream)
{
    const float* x   = (const float*)d_in[0];
    float*       out = (float*)d_out;
    const int n_rows = in_sizes[0] / N;   // 4096
    cumprod_rows_kernel<<<n_rows, T, 0, stream>>>(x, out, n_rows);
}